// Round 5
// baseline (1652.016 us; speedup 1.0000x reference)
//
#include <hip/hip_runtime.h>

typedef __bf16  bf16x8 __attribute__((ext_vector_type(8)));
typedef float   f32x4  __attribute__((ext_vector_type(4)));

__device__ __constant__ int EDGE_A[19] = {1,8,9,1,11,12,1,2,3,2,1,5,6,5,0,0,0,14,15};
__device__ __constant__ int EDGE_B[19] = {8,9,10,11,12,13,2,3,4,16,5,6,7,17,1,14,15,16,17};

__device__ __forceinline__ unsigned short f2bf(float f) {
    unsigned int x = __float_as_uint(f);
    x += 0x7FFFu + ((x >> 16) & 1u);
    return (unsigned short)(x >> 16);
}

// XOR-swizzle on LDS byte offsets: flips the 16B sub-block bits by pixel low
// bits -> each wave's access spreads uniformly over all 8 granule positions.
// MASK=48 for 64B/pixel rows, MASK=16 for 32B/pixel rows.
template<int MASK>
__device__ __forceinline__ int sw(int lin) { return lin ^ ((lin >> 3) & MASK); }

// ---------------------------------------------------------------------------
// Weight pre-pass -> A-fragment layout (lane m=oc=idx&15 holds k=quad*8+j).
//   W1 @0     : 13 tap-pairs x 1 x 16 x 32   6656   (k = h*16+ic, t=2tp+h)
//   W2 @6656  : 13 x 2 x 16 x 32            13312
//   W3 @19968 : 25 taps x 2 x 16 x 32       25600   (k = ic)
//   W4 @45568 : 25 x 2 x 16 x 32            25600
//   W5 @71168 : 8 x 16 x 32                  4096
//   W0 @75264 : 4 chunks x 16 x 32           2048   (k = tl*4+ic, t=c*8+tl)
// ---------------------------------------------------------------------------
extern "C" __global__ void __launch_bounds__(256)
reorder_weights(const float* __restrict__ w0, const float* __restrict__ w1,
                const float* __restrict__ w2, const float* __restrict__ w3,
                const float* __restrict__ w4, const float* __restrict__ w5,
                unsigned short* __restrict__ ws)
{
    int idx = blockIdx.x * 256 + threadIdx.x;
    if (idx < 6656) {
        int k = idx & 31, n = (idx >> 5) & 15, tp = idx >> 9;
        int t = 2 * tp + (k >> 4), ic = k & 15;
        float v = (t < 25) ? w1[(n * 16 + ic) * 25 + t] : 0.f;
        ws[idx] = f2bf(v);
    } else if (idx < 19968) {
        int j = idx - 6656;
        int k = j & 31, n = (j >> 5) & 15, nt = (j >> 9) & 1, tp = j >> 10;
        int t = 2 * tp + (k >> 4), ic = k & 15, oc = nt * 16 + n;
        float v = (t < 25) ? w2[(oc * 16 + ic) * 25 + t] : 0.f;
        ws[idx] = f2bf(v);
    } else if (idx < 45568) {
        int j = idx - 19968;
        int k = j & 31, n = (j >> 5) & 15, nt = (j >> 9) & 1, tap = j >> 10;
        ws[idx] = f2bf(w3[((nt * 16 + n) * 32 + k) * 25 + tap]);
    } else if (idx < 71168) {
        int j = idx - 45568;
        int k = j & 31, n = (j >> 5) & 15, nt = (j >> 9) & 1, tap = j >> 10;
        ws[idx] = f2bf(w4[((nt * 16 + n) * 32 + k) * 25 + tap]);
    } else if (idx < 75264) {
        int j = idx - 71168;
        int k = j & 31, oc = j >> 5;
        ws[idx] = f2bf(w5[oc * 32 + k]);
    } else if (idx < 77312) {
        int j = idx - 75264;
        int k = j & 31, n = (j >> 5) & 15, c = j >> 9;
        int t = c * 8 + (k >> 2), ic = k & 3;
        float v = (t < 25) ? w0[(n * 4 + ic) * 25 + t] : 0.f;
        ws[idx] = f2bf(v);
    }
}

__device__ __forceinline__ ushort4 pack_relu4(f32x4 a, float4 b, bool oob) {
    ushort4 us;
    us.x = oob ? 0 : f2bf(fmaxf(a[0] + b.x, 0.f));
    us.y = oob ? 0 : f2bf(fmaxf(a[1] + b.y, 0.f));
    us.z = oob ? 0 : f2bf(fmaxf(a[2] + b.z, 0.f));
    us.w = oob ? 0 : f2bf(fmaxf(a[3] + b.w, 0.f));
    return us;
}

// ---------------------------------------------------------------------------
// Paired-tap 5x5 stage (CIN=16): A=weights VGPR-resident in chunks of <=5
// (20 VGPRs, keeps arch-reg pressure under the 64-reg split -> no spills),
// B=pixels. LDS reads/writes XOR-swizzled.
// ---------------------------------------------------------------------------
template<int SIN, int SOUT, int NT, int MAXM, bool GUARD>
__device__ __forceinline__ void conv_paired(
    const unsigned char* __restrict__ sinB, unsigned char* __restrict__ soutB,
    const unsigned short* __restrict__ wA, const float* __restrict__ bias,
    int gy0, int gx0, int wave, int lane)
{
    constexpr int NM    = (SOUT * SOUT) / 16;
    constexpr int WN    = (NT == 2) ? 4 : 8;
    constexpr int TSTR  = NT * 512;
    constexpr int OMASK = (NT == 1) ? 16 : 48;
    const int nl = lane & 15, quad = lane >> 4;
    const int h = quad >> 1;
    const int coff = (quad & 1) * 16;            // byte offset of k sub-block
    const int nt   = (NT == 2) ? (wave & 1) : 0;
    const int wset = (NT == 2) ? (wave >> 1) : wave;

    int abase[MAXM];
#pragma unroll
    for (int i = 0; i < MAXM; ++i) {
        int mt = wset + WN * i;
        if (!GUARD || mt < NM) {
            int p = mt * 16 + nl;
            int y = p / SOUT, x = p - y * SOUT;
            abase[i] = (y * SIN + x) * 32 + coff;
        }
    }
    f32x4 acc[MAXM];
#pragma unroll
    for (int i = 0; i < MAXM; ++i) acc[i] = (f32x4)0.f;

    const unsigned short* wp = wA + nt * 512 + nl * 32 + quad * 8;

    bf16x8 wf[5];
#pragma unroll
    for (int c = 0; c < 3; ++c) {
        const int c0 = c * 5;
        const int cn = (c == 2) ? 3 : 5;
#pragma unroll
        for (int tp = 0; tp < 5; ++tp)
            if (tp < cn) wf[tp] = *(const bf16x8*)(wp + (c0 + tp) * TSTR);
#pragma unroll
        for (int tp = 0; tp < 5; ++tp) {
            if (tp < cn) {
                int t = 2 * (c0 + tp) + h;
                if (t > 24) t = 24;              // padded half; weights zero
                int dy = t / 5, dx = t - 5 * dy;
                int toff = (dy * SIN + dx) * 32;
#pragma unroll
                for (int i = 0; i < MAXM; ++i)
                    if (!GUARD || wset + WN * i < NM) {
                        int lin = abase[i] + toff;
                        bf16x8 a = *(const bf16x8*)(sinB + sw<16>(lin));
                        acc[i] = __builtin_amdgcn_mfma_f32_16x16x32_bf16(wf[tp], a, acc[i], 0, 0, 0);
                    }
            }
        }
    }

    float4 bb = *(const float4*)(bias + nt * 16 + quad * 4);
#pragma unroll
    for (int i = 0; i < MAXM; ++i) {
        int mt = wset + WN * i;
        if (!GUARD || mt < NM) {
            int p = mt * 16 + nl;
            int y = p / SOUT, x = p - y * SOUT;
            bool oob = ((unsigned)(gy0 + y) >= 128u) || ((unsigned)(gx0 + x) >= 128u);
            int lin = p * (NT * 32) + nt * 32 + quad * 8;
            *(ushort4*)(soutB + sw<OMASK>(lin)) = pack_relu4(acc[i], bb, oob);
        }
    }
}

// ---------------------------------------------------------------------------
// CIN=32 5x5 stage (k=ic), NT=2. Weight chunks of 5 (20 VGPRs). Swizzled LDS.
// ---------------------------------------------------------------------------
template<int SIN, int SOUT, int MAXM, bool GUARD>
__device__ __forceinline__ void conv_c32(
    const unsigned char* __restrict__ sinB, unsigned char* __restrict__ soutB,
    const unsigned short* __restrict__ wA, const float* __restrict__ bias,
    int gy0, int gx0, int wave, int lane)
{
    constexpr int NM = (SOUT * SOUT) / 16;
    const int nl = lane & 15, quad = lane >> 4;
    const int nt = wave & 1, wset = wave >> 1;

    int abase[MAXM];
#pragma unroll
    for (int i = 0; i < MAXM; ++i) {
        int mt = wset + 4 * i;
        if (!GUARD || mt < NM) {
            int p = mt * 16 + nl;
            int y = p / SOUT, x = p - y * SOUT;
            abase[i] = (y * SIN + x) * 64 + quad * 16;
        }
    }
    f32x4 acc[MAXM];
#pragma unroll
    for (int i = 0; i < MAXM; ++i) acc[i] = (f32x4)0.f;

    const unsigned short* wp = wA + nt * 512 + nl * 32 + quad * 8;

    bf16x8 wf[5];
#pragma unroll
    for (int c = 0; c < 5; ++c) {
#pragma unroll
        for (int tp = 0; tp < 5; ++tp)
            wf[tp] = *(const bf16x8*)(wp + (c * 5 + tp) * 1024);
#pragma unroll
        for (int tp = 0; tp < 5; ++tp) {
            int t = c * 5 + tp;
            int dy = t / 5, dx = t - 5 * dy;
            int toff = (dy * SIN + dx) * 64;
#pragma unroll
            for (int i = 0; i < MAXM; ++i)
                if (!GUARD || wset + 4 * i < NM) {
                    int lin = abase[i] + toff;
                    bf16x8 a = *(const bf16x8*)(sinB + sw<48>(lin));
                    acc[i] = __builtin_amdgcn_mfma_f32_16x16x32_bf16(wf[tp], a, acc[i], 0, 0, 0);
                }
        }
    }

    float4 bb = *(const float4*)(bias + nt * 16 + quad * 4);
#pragma unroll
    for (int i = 0; i < MAXM; ++i) {
        int mt = wset + 4 * i;
        if (!GUARD || mt < NM) {
            int p = mt * 16 + nl;
            int y = p / SOUT, x = p - y * SOUT;
            bool oob = ((unsigned)(gy0 + y) >= 128u) || ((unsigned)(gx0 + x) >= 128u);
            int lin = p * 64 + nt * 32 + quad * 8;
            *(ushort4*)(soutB + sw<48>(lin)) = pack_relu4(acc[i], bb, oob);
        }
    }
}

// ---------------------------------------------------------------------------
// Fused pipeline: one 512-thread block = one 16x16 output tile.
// LDS (65536 B): s_in@0 10368 | s0@32768 32768 | s1@0 25088 | s2@28672 36864
//                | s3@0 25600 | s4@49152 16384   (ping-pong, no overlaps)
// ---------------------------------------------------------------------------
extern "C" __global__ void __launch_bounds__(512, 4)
gnn_paf_mfma(const float* __restrict__ cnn, const unsigned short* __restrict__ wB,
             const float* __restrict__ b0, const float* __restrict__ b1,
             const float* __restrict__ b2, const float* __restrict__ b3,
             const float* __restrict__ b4, const float* __restrict__ b5,
             const float* __restrict__ w6, const float* __restrict__ b6,
             float* __restrict__ out)
{
    __shared__ __align__(64) unsigned char smem[65536];
    unsigned short* s_in = (unsigned short*)(smem);
    unsigned char*  s0   = smem + 32768;
    unsigned char*  s1   = smem;
    unsigned char*  s2   = smem + 28672;
    unsigned char*  s3   = smem;
    unsigned char*  s4   = smem + 49152;

    const int tid  = threadIdx.x;
    const int lane = tid & 63, wave = tid >> 6;
    const int tile = blockIdx.x, img = blockIdx.y;
    const int oy = (tile >> 3) * 16, ox = (tile & 7) * 16;
    const int n = img / 19, g = img - n * 19;
    const int ch0 = EDGE_A[g], ch1 = EDGE_B[g], ch2 = 19 + 2 * g, ch3 = 20 + 2 * g;
    const int nl = lane & 15, quad = lane >> 4;

    // ---- gather -> s_in bf16 HWC4 (36x36 halo, zero-padded; 8B rows, no swizzle)
    {
        const long long nb = (long long)n * 57 * 16384;
        for (int p = tid; p < 1296; p += 512) {
            int r = p / 36, col = p - r * 36;
            int gy = oy - 10 + r, gx = ox - 10 + col;
            ushort4 v = {0, 0, 0, 0};
            if ((unsigned)gy < 128u && (unsigned)gx < 128u) {
                int off = gy * 128 + gx;
                v.x = f2bf(cnn[nb + (long long)ch0 * 16384 + off]);
                v.y = f2bf(cnn[nb + (long long)ch1 * 16384 + off]);
                v.z = f2bf(cnn[nb + (long long)ch2 * 16384 + off]);
                v.w = f2bf(cnn[nb + (long long)ch3 * 16384 + off]);
            }
            *(ushort4*)(s_in + p * 4) = v;
        }
    }
    __syncthreads();

    // ---- conv0 (4->16) MFMA: K=32 = 8 taps x 4 ch, 4 chunks
    {
        bf16x8 wf[4];
#pragma unroll
        for (int c = 0; c < 4; ++c)
            wf[c] = *(const bf16x8*)(wB + 75264 + c * 512 + nl * 32 + quad * 8);
        float4 bb = *(const float4*)(b0 + quad * 4);
#pragma unroll 1
        for (int i = 0; i < 8; ++i) {
            int mt = wave + 8 * i;                 // 64 mtiles
            int p = mt * 16 + nl;
            int y = p >> 5, x = p & 31;
            f32x4 acc = (f32x4)0.f;
#pragma unroll
            for (int c = 0; c < 4; ++c) {
                int t0 = c * 8 + quad * 2, t1 = t0 + 1;
                if (t0 > 24) t0 = 24;
                if (t1 > 24) t1 = 24;              // padded taps; weights zero
                int dy0 = t0 / 5, dx0 = t0 - 5 * dy0;
                int dy1 = t1 / 5, dx1 = t1 - 5 * dy1;
                uint2 lo = *(const uint2*)(s_in + ((y + dy0) * 36 + x + dx0) * 4);
                uint2 hi = *(const uint2*)(s_in + ((y + dy1) * 36 + x + dx1) * 4);
                bf16x8 a;
                ((uint2*)&a)[0] = lo;
                ((uint2*)&a)[1] = hi;
                acc = __builtin_amdgcn_mfma_f32_16x16x32_bf16(wf[c], a, acc, 0, 0, 0);
            }
            bool oob = ((unsigned)(oy - 8 + y) >= 128u) || ((unsigned)(ox - 8 + x) >= 128u);
            int lin = p * 32 + quad * 8;
            *(ushort4*)(s0 + sw<16>(lin)) = pack_relu4(acc, bb, oob);
        }
    }
    __syncthreads();

    conv_paired<32, 28, 1, 7, true >(s0, s1, wB + 0,     b1, oy - 6, ox - 6, wave, lane);
    __syncthreads();
    conv_paired<28, 24, 2, 9, false>(s1, s2, wB + 6656,  b2, oy - 4, ox - 4, wave, lane);
    __syncthreads();
    conv_c32   <24, 20, 7, true >(s2, s3, wB + 19968, b3, oy - 2, ox - 2, wave, lane);
    __syncthreads();
    conv_c32   <20, 16, 4, false>(s3, s4, wB + 45568, b4, oy,     ox,     wave, lane);
    __syncthreads();

    // ---- conv5 (1x1 32->128) + relu + conv6 (128->2), weights VGPR-resident
    {
        bf16x8 w5f[8];
#pragma unroll
        for (int nt = 0; nt < 8; ++nt)
            w5f[nt] = *(const bf16x8*)(wB + 71168 + nt * 512 + nl * 32 + quad * 8);
        const float b6q = b6[quad & 1];
#pragma unroll 1
        for (int ii = 0; ii < 2; ++ii) {
            int mt = wave + 8 * ii;                // 16 mtiles
            int lin = (mt * 16 + nl) * 64 + quad * 16;
            bf16x8 pf = *(const bf16x8*)(s4 + sw<48>(lin));
            float o0 = 0.f, o1 = 0.f;
#pragma unroll
            for (int nt = 0; nt < 8; ++nt) {
                f32x4 acc = (f32x4)0.f;
                acc = __builtin_amdgcn_mfma_f32_16x16x32_bf16(w5f[nt], pf, acc, 0, 0, 0);
                float4 bb  = *(const float4*)(b5 + nt * 16 + quad * 4);
                float4 wa  = *(const float4*)(w6 + nt * 16 + quad * 4);
                float4 wb2 = *(const float4*)(w6 + 128 + nt * 16 + quad * 4);
                float h0 = fmaxf(acc[0] + bb.x, 0.f), h1 = fmaxf(acc[1] + bb.y, 0.f);
                float h2 = fmaxf(acc[2] + bb.z, 0.f), h3 = fmaxf(acc[3] + bb.w, 0.f);
                o0 = fmaf(h0, wa.x, fmaf(h1, wa.y, fmaf(h2, wa.z, fmaf(h3, wa.w, o0))));
                o1 = fmaf(h0, wb2.x, fmaf(h1, wb2.y, fmaf(h2, wb2.z, fmaf(h3, wb2.w, o1))));
            }
            o0 += __shfl_xor(o0, 16, 64); o0 += __shfl_xor(o0, 32, 64);
            o1 += __shfl_xor(o1, 16, 64); o1 += __shfl_xor(o1, 32, 64);
            if (quad < 2) {
                float val = ((quad == 0) ? o0 : o1) + b6q;
                long long ob = (((long long)n * 38 + 2 * g + quad) * 128 + (oy + mt)) * 128 + (ox + nl);
                out[ob] = val;
            }
        }
    }
}

extern "C" void kernel_launch(void* const* d_in, const int* in_sizes, int n_in,
                              void* d_out, int out_size, void* d_ws, size_t ws_size,
                              hipStream_t stream) {
    const float* cnn = (const float*)d_in[0];
    const float* w0 = (const float*)d_in[2];  const float* b0 = (const float*)d_in[3];
    const float* w1 = (const float*)d_in[4];  const float* b1 = (const float*)d_in[5];
    const float* w2 = (const float*)d_in[6];  const float* b2 = (const float*)d_in[7];
    const float* w3 = (const float*)d_in[8];  const float* b3 = (const float*)d_in[9];
    const float* w4 = (const float*)d_in[10]; const float* b4 = (const float*)d_in[11];
    const float* w5 = (const float*)d_in[12]; const float* b5 = (const float*)d_in[13];
    const float* w6 = (const float*)d_in[14]; const float* b6 = (const float*)d_in[15];
    float* out = (float*)d_out;
    unsigned short* wB = (unsigned short*)d_ws;   // 154,624 B used

    hipLaunchKernelGGL(reorder_weights, dim3(302), dim3(256), 0, stream,
                       w0, w1, w2, w3, w4, w5, wB);
    hipLaunchKernelGGL(gnn_paf_mfma, dim3(64, 304), dim3(512), 0, stream,
                       cnn, wB, b0, b1, b2, b3, b4, b5, w6, b6, out);
}